// Round 12
// baseline (69.038 us; speedup 1.0000x reference)
//
#include <hip/hip_runtime.h>
#include <hip/hip_bf16.h>
#include <math.h>

typedef __attribute__((ext_vector_type(8))) _Float16 half8;
typedef __attribute__((ext_vector_type(2))) _Float16 half2v;
typedef __attribute__((ext_vector_type(4))) float f32x4;
typedef __attribute__((ext_vector_type(4))) unsigned int u32x4;

#define NPT 1024
#define D   128

__device__ __forceinline__ unsigned int absdiff_pk(unsigned int a, unsigned int b) {
  half2v d = __builtin_bit_cast(half2v, a) - __builtin_bit_cast(half2v, b);
  return __builtin_bit_cast(unsigned int, d) & 0x7FFF7FFFu;
}
__device__ __forceinline__ unsigned int pk_max(unsigned int a, unsigned int b) {
  unsigned int r;
  asm("v_pk_max_f16 %0, %1, %2" : "=v"(r) : "v"(a), "v"(b));
  return r;
}
__device__ __forceinline__ unsigned int pkrtz(float lo, float hi) {
  return __builtin_bit_cast(unsigned int, __builtin_amdgcn_cvt_pkrtz(lo, hi));
}
__device__ __forceinline__ float fdot2(unsigned int a, unsigned int b, float c) {
  return __builtin_amdgcn_fdot2(__builtin_bit_cast(half2v, a),
                                __builtin_bit_cast(half2v, b), c, false);
}

// ---------------- kernel 1: prep ----------------
// xsw: swizzled f16 x: row i base i*256B, elem k at ((2k)^((i&7)<<4))
// w1p: fragment-ordered f16 W1: w1p[((k>>3)*128+hid)*8 + (k&7)] = W1[k][hid]
// xwghT: f16 [128 t][1024 i] transpose of x@Wg
__global__ __launch_bounds__(128) void k_prep(const float* __restrict__ x,
                                              const float* __restrict__ W1,
                                              const float* __restrict__ Wg,
                                              float* __restrict__ deg,
                                              unsigned short* __restrict__ xsw,
                                              unsigned short* __restrict__ w1p,
                                              unsigned short* __restrict__ xwghT) {
  __shared__ float xi[D];
  const int i = blockIdx.x;
  const int t = threadIdx.x;
  const float xv = x[i * D + t];
  xi[t] = xv;
  if (t == 0) deg[i] = 0.f;
  const _Float16 hv = (_Float16)xv;
  const int byte = i * 256 + ((2 * t) ^ ((i & 7) << 4));
  *(unsigned short*)((unsigned char*)xsw + byte) =
      __builtin_bit_cast(unsigned short, hv);
  if (i < 128) {  // t = k, i = hid
    const _Float16 wv = (_Float16)W1[t * 128 + i];
    w1p[((t >> 3) * 128 + i) * 8 + (t & 7)] = __builtin_bit_cast(unsigned short, wv);
  }
  __syncthreads();
  float acc = 0.f;
#pragma unroll 8
  for (int k = 0; k < D; ++k) acc += xi[k] * Wg[k * D + t];
  const _Float16 av = (_Float16)acc;
  xwghT[t * NPT + i] = __builtin_bit_cast(unsigned short, av);
}

// ---------------- kernel 2: adjacency, f16 MFMA (R7 form + deferred finish) ----
// grid (256,2) x 256 thr. Wave = 1 i-row x 512 j (32 sequential groups of 16).
// Full 128-hid W1 in 128 regs (AGPR side). No LDS, no barriers.
// Group g-1's reduce/sigmoid/store runs in group g's MFMA shadow (1 carry reg).
__global__ __launch_bounds__(256, 2) void k_adj(const unsigned short* __restrict__ xsw,
                                                const unsigned short* __restrict__ w1p,
                                                const float* __restrict__ b1,
                                                const float* __restrict__ W2,
                                                const float* __restrict__ b2,
                                                float* __restrict__ adj,
                                                float* __restrict__ deg) {
  const int tid  = threadIdx.x;
  const int lane = tid & 63;
  const int w    = tid >> 6;   // 0..3
  const int l15  = lane & 15;
  const int g    = lane >> 4;  // 0..3
  const int i  = blockIdx.x * 4 + w;
  const int jq = blockIdx.y;   // 0..1

  // W1 -> regs: A[m=hid][k], hid = ht*16+l15, k = ks*32+g*8+e
  half8 w1f[4][8];
#pragma unroll
  for (int ks = 0; ks < 4; ++ks)
#pragma unroll
    for (int ht = 0; ht < 8; ++ht)
      w1f[ks][ht] = *(const half8*)(w1p + ((ks * 4 + g) * 128 + ht * 16 + l15) * 8);

  // relu(a+b1)*w2 = max(a,-b1)*w2 + b1*w2
  unsigned int nb1pk[8][2], w2pk[8][2];
  float c0 = 0.f;
#pragma unroll
  for (int ht = 0; ht < 8; ++ht) {
    const f32x4 bv = *(const f32x4*)&b1[ht * 16 + g * 4];
    const f32x4 wv = *(const f32x4*)&W2[ht * 16 + g * 4];
    c0 += bv[0] * wv[0] + bv[1] * wv[1] + bv[2] * wv[2] + bv[3] * wv[3];
    nb1pk[ht][0] = pkrtz(-bv[0], -bv[1]);
    nb1pk[ht][1] = pkrtz(-bv[2], -bv[3]);
    w2pk[ht][0] = pkrtz(wv[0], wv[1]);
    w2pk[ht][1] = pkrtz(wv[2], wv[3]);
  }
  c0 += __shfl_xor(c0, 16);
  c0 += __shfl_xor(c0, 32);
  const float B2 = b2[0] + c0;

  // xi fragments (broadcast row i)
  const unsigned char* xsb = (const unsigned char*)xsw;
  const unsigned char* xrow = xsb + i * 256;
  const int sxI = (i & 7) << 4;
  u32x4 xiu[4];
#pragma unroll
  for (int ks = 0; ks < 4; ++ks)
    xiu[ks] = *(const u32x4*)(xrow + ((ks * 64 + g * 16) ^ sxI));

  const int sxJ = (l15 & 7) << 4;
  const unsigned char* jrow = xsb + (jq * 512 + l15) * 256;
  const int kb0 = (0 * 64 + g * 16) ^ sxJ;
  const int kb1 = (1 * 64 + g * 16) ^ sxJ;
  const int kb2 = (2 * 64 + g * 16) ^ sxJ;
  const int kb3 = (3 * 64 + g * 16) ^ sxJ;

  u32x4 jr0 = *(const u32x4*)(jrow + kb0);
  u32x4 jr1 = *(const u32x4*)(jrow + kb1);
  u32x4 jr2 = *(const u32x4*)(jrow + kb2);
  u32x4 jr3 = *(const u32x4*)(jrow + kb3);

  f32x4 acc[8];

  // loads + absdiff + 32 MFMA for current group; prefetch group grp+1
  auto phase = [&](int grp) {
    const unsigned char* nrow = jrow + (grp + 1) * 4096;
#pragma unroll
    for (int ht = 0; ht < 8; ++ht) acc[ht] = f32x4{0.f, 0.f, 0.f, 0.f};
    __builtin_amdgcn_s_setprio(1);
    {
      u32x4 afu;
#pragma unroll
      for (int p4 = 0; p4 < 4; ++p4) afu[p4] = absdiff_pk(jr0[p4], xiu[0][p4]);
      if (grp < 31) jr0 = *(const u32x4*)(nrow + kb0);
      const half8 af = __builtin_bit_cast(half8, afu);
#pragma unroll
      for (int ht = 0; ht < 8; ++ht)
        acc[ht] = __builtin_amdgcn_mfma_f32_16x16x32_f16(w1f[0][ht], af, acc[ht], 0, 0, 0);
    }
    {
      u32x4 afu;
#pragma unroll
      for (int p4 = 0; p4 < 4; ++p4) afu[p4] = absdiff_pk(jr1[p4], xiu[1][p4]);
      if (grp < 31) jr1 = *(const u32x4*)(nrow + kb1);
      const half8 af = __builtin_bit_cast(half8, afu);
#pragma unroll
      for (int ht = 0; ht < 8; ++ht)
        acc[ht] = __builtin_amdgcn_mfma_f32_16x16x32_f16(w1f[1][ht], af, acc[ht], 0, 0, 0);
    }
    {
      u32x4 afu;
#pragma unroll
      for (int p4 = 0; p4 < 4; ++p4) afu[p4] = absdiff_pk(jr2[p4], xiu[2][p4]);
      if (grp < 31) jr2 = *(const u32x4*)(nrow + kb2);
      const half8 af = __builtin_bit_cast(half8, afu);
#pragma unroll
      for (int ht = 0; ht < 8; ++ht)
        acc[ht] = __builtin_amdgcn_mfma_f32_16x16x32_f16(w1f[2][ht], af, acc[ht], 0, 0, 0);
    }
    {
      u32x4 afu;
#pragma unroll
      for (int p4 = 0; p4 < 4; ++p4) afu[p4] = absdiff_pk(jr3[p4], xiu[3][p4]);
      if (grp < 31) jr3 = *(const u32x4*)(nrow + kb3);
      const half8 af = __builtin_bit_cast(half8, afu);
#pragma unroll
      for (int ht = 0; ht < 8; ++ht)
        acc[ht] = __builtin_amdgcn_mfma_f32_16x16x32_f16(w1f[3][ht], af, acc[ht], 0, 0, 0);
    }
    __builtin_amdgcn_s_setprio(0);
  };

  // dot: pkrtz+max -> 4 parallel fdot2 chains (pre-reduce partial)
  auto dot = [&]() -> float {
    float sA = 0.f, sB = 0.f, sC = 0.f, sD = 0.f;
#pragma unroll
    for (int ht = 0; ht < 8; ht += 2) {
      unsigned int h0a = pk_max(pkrtz(acc[ht][0], acc[ht][1]), nb1pk[ht][0]);
      unsigned int h0b = pk_max(pkrtz(acc[ht][2], acc[ht][3]), nb1pk[ht][1]);
      unsigned int h1a = pk_max(pkrtz(acc[ht + 1][0], acc[ht + 1][1]), nb1pk[ht + 1][0]);
      unsigned int h1b = pk_max(pkrtz(acc[ht + 1][2], acc[ht + 1][3]), nb1pk[ht + 1][1]);
      sA = fdot2(h0a, w2pk[ht][0], sA);
      sB = fdot2(h0b, w2pk[ht][1], sB);
      sC = fdot2(h1a, w2pk[ht + 1][0], sC);
      sD = fdot2(h1b, w2pk[ht + 1][1], sD);
    }
    return (sA + sB) + (sC + sD);
  };

  float degacc = 0.f;
  float s_prev;

  phase(0);
  s_prev = dot();
#pragma unroll 1
  for (int grp = 1; grp < 32; ++grp) {
    phase(grp);  // MFMA issues for grp (acc-dependent work deferred to dot())
    // deferred finish of grp-1: independent of in-flight MFMAs
    float sr = s_prev;
    sr += __shfl_xor(sr, 16);
    sr += __shfl_xor(sr, 32);
    if (lane < 16) {
      const float sig = 1.f / (1.f + __expf(-(sr + B2)));
      adj[i * NPT + jq * 512 + (grp - 1) * 16 + l15] = sig;
      degacc += sig;
    }
    s_prev = dot();
  }
  {
    float sr = s_prev;
    sr += __shfl_xor(sr, 16);
    sr += __shfl_xor(sr, 32);
    if (lane < 16) {
      const float sig = 1.f / (1.f + __expf(-(sr + B2)));
      adj[i * NPT + jq * 512 + 31 * 16 + l15] = sig;
      degacc += sig;
    }
  }
  if (lane < 16) {
#pragma unroll
    for (int m = 1; m <= 8; m <<= 1) degacc += __shfl_xor(degacc, m);
    if (l15 == 0) atomicAdd(&deg[i], degacc);
  }
}

// ---------------- kernel 3: fused d1 (dinv-LDS prologue, MFMA, leaky epilogue) ----
// out[i][t] = leaky( dinv_i * sum_j xwghT[t][j]*(adj[i][j]*dinv_j) + bg[t] )
// grid 64 x 256 thr (4 waves). Block: 16 i x ALL 128 t. adj read exactly once.
__global__ __launch_bounds__(256) void k_d1(const float* __restrict__ adj,
                                            const unsigned short* __restrict__ xwghT,
                                            const float* __restrict__ deg,
                                            const float* __restrict__ bg,
                                            float* __restrict__ outp) {
  __shared__ unsigned short dvh[NPT];
  const int tid  = threadIdx.x;
  const int lane = tid & 63;
  const int w    = tid >> 6;
  const int l15  = lane & 15;
  const int g    = lane >> 4;
  const int i0 = blockIdx.x * 16;

#pragma unroll
  for (int it = 0; it < 4; ++it) {
    const int idx = it * 256 + tid;
    const _Float16 dh = (_Float16)rsqrtf(deg[idx]);
    dvh[idx] = __builtin_bit_cast(unsigned short, dh);
  }
  __syncthreads();

  f32x4 acc[2] = {f32x4{0.f, 0.f, 0.f, 0.f}, f32x4{0.f, 0.f, 0.f, 0.f}};
#pragma unroll 2
  for (int ch = 0; ch < 32; ++ch) {
    const int kofs = ch * 32 + g * 8;
    const f32x4 av0 = *(const f32x4*)&adj[(i0 + l15) * NPT + kofs];
    const f32x4 av1 = *(const f32x4*)&adj[(i0 + l15) * NPT + kofs + 4];
    const half2v* dq = (const half2v*)(dvh + kofs);
    u32x4 bu;
    bu[0] = __builtin_bit_cast(unsigned int,
        half2v(__builtin_bit_cast(half2v, pkrtz(av0[0], av0[1])) * dq[0]));
    bu[1] = __builtin_bit_cast(unsigned int,
        half2v(__builtin_bit_cast(half2v, pkrtz(av0[2], av0[3])) * dq[1]));
    bu[2] = __builtin_bit_cast(unsigned int,
        half2v(__builtin_bit_cast(half2v, pkrtz(av1[0], av1[1])) * dq[2]));
    bu[3] = __builtin_bit_cast(unsigned int,
        half2v(__builtin_bit_cast(half2v, pkrtz(av1[2], av1[3])) * dq[3]));
    const half8 bf = __builtin_bit_cast(half8, bu);
#pragma unroll
    for (int tt = 0; tt < 2; ++tt) {
      const int trow = w * 32 + tt * 16 + l15;
      const half8 af = *(const half8*)(xwghT + trow * NPT + kofs);
      acc[tt] = __builtin_amdgcn_mfma_f32_16x16x32_f16(af, bf, acc[tt], 0, 0, 0);
    }
  }
  const float di = rsqrtf(deg[i0 + l15]);
#pragma unroll
  for (int tt = 0; tt < 2; ++tt) {
    const int t0 = w * 32 + tt * 16;
    const f32x4 bgv = *(const f32x4*)&bg[t0 + g * 4];
    f32x4 o;
#pragma unroll
    for (int r = 0; r < 4; ++r) {
      const float v = acc[tt][r] * di + bgv[r];
      o[r] = v > 0.f ? v : 0.2f * v;
    }
    *(f32x4*)&outp[(i0 + l15) * D + t0 + g * 4] = o;
  }
}

extern "C" void kernel_launch(void* const* d_in, const int* in_sizes, int n_in,
                              void* d_out, int out_size, void* d_ws, size_t ws_size,
                              hipStream_t stream) {
  const float* x  = (const float*)d_in[0];
  const float* W1 = (const float*)d_in[1];
  const float* b1 = (const float*)d_in[2];
  const float* W2 = (const float*)d_in[3];
  const float* b2 = (const float*)d_in[4];
  const float* Wg = (const float*)d_in[5];
  const float* bg = (const float*)d_in[6];

  float* outp = (float*)d_out;                  // [1024*128]
  float* adj  = outp + NPT * D;                 // [1024*1024]
  unsigned char* ws = (unsigned char*)d_ws;
  float* deg            = (float*)ws;                               // 4KB @0
  unsigned short* xsw   = (unsigned short*)(ws + 4096);             // 256KB
  unsigned short* w1p   = (unsigned short*)(ws + 4096 + 262144);    // 32KB
  unsigned short* xwghT = (unsigned short*)(ws + 4096 + 262144 + 32768);  // 256KB

  k_prep<<<NPT, 128, 0, stream>>>(x, W1, Wg, deg, xsw, w1p, xwghT);
  k_adj<<<dim3(256, 2), 256, 0, stream>>>(xsw, w1p, b1, W2, b2, adj, deg);
  k_d1<<<64, 256, 0, stream>>>(adj, xwghT, deg, bg, outp);
}

// Round 13
// 67.277 us; speedup vs baseline: 1.0262x; 1.0262x over previous
//
#include <hip/hip_runtime.h>
#include <hip/hip_bf16.h>
#include <math.h>

typedef __attribute__((ext_vector_type(8))) _Float16 half8;
typedef __attribute__((ext_vector_type(2))) _Float16 half2v;
typedef __attribute__((ext_vector_type(4))) float f32x4;
typedef __attribute__((ext_vector_type(4))) unsigned int u32x4;

#define NPT 1024
#define D   128

__device__ __forceinline__ unsigned int absdiff_pk(unsigned int a, unsigned int b) {
  half2v d = __builtin_bit_cast(half2v, a) - __builtin_bit_cast(half2v, b);
  return __builtin_bit_cast(unsigned int, d) & 0x7FFF7FFFu;
}
__device__ __forceinline__ unsigned int pk_max(unsigned int a, unsigned int b) {
  unsigned int r;
  asm("v_pk_max_f16 %0, %1, %2" : "=v"(r) : "v"(a), "v"(b));
  return r;
}
__device__ __forceinline__ unsigned int pkrtz(float lo, float hi) {
  return __builtin_bit_cast(unsigned int, __builtin_amdgcn_cvt_pkrtz(lo, hi));
}
__device__ __forceinline__ float fdot2(unsigned int a, unsigned int b, float c) {
  return __builtin_amdgcn_fdot2(__builtin_bit_cast(half2v, a),
                                __builtin_bit_cast(half2v, b), c, false);
}

// ---------------- kernel 1: prep ----------------
// xsw: swizzled f16 x: row i base i*256B, elem k at ((2k)^((i&7)<<4))
// w1p: fragment-ordered f16 W1: w1p[((k>>3)*128+hid)*8 + (k&7)] = W1[k][hid]
// xwghT: f16 [128 t][1024 i] transpose of x@Wg
__global__ __launch_bounds__(128) void k_prep(const float* __restrict__ x,
                                              const float* __restrict__ W1,
                                              const float* __restrict__ Wg,
                                              unsigned short* __restrict__ xsw,
                                              unsigned short* __restrict__ w1p,
                                              unsigned short* __restrict__ xwghT) {
  __shared__ float xi[D];
  const int i = blockIdx.x;
  const int t = threadIdx.x;
  const float xv = x[i * D + t];
  xi[t] = xv;
  const _Float16 hv = (_Float16)xv;
  const int byte = i * 256 + ((2 * t) ^ ((i & 7) << 4));
  *(unsigned short*)((unsigned char*)xsw + byte) =
      __builtin_bit_cast(unsigned short, hv);
  if (i < 128) {  // t = k, i = hid
    const _Float16 wv = (_Float16)W1[t * 128 + i];
    w1p[((t >> 3) * 128 + i) * 8 + (t & 7)] = __builtin_bit_cast(unsigned short, wv);
  }
  __syncthreads();
  float acc = 0.f;
#pragma unroll 8
  for (int k = 0; k < D; ++k) acc += xi[k] * Wg[k * D + t];
  const _Float16 av = (_Float16)acc;
  xwghT[t * NPT + i] = __builtin_bit_cast(unsigned short, av);
}

// ---------------- kernel 2: adjacency, f16 MFMA (R7 loop, triangular skip) ----
// grid (256,4) x 256 thr. Wave = 1 i-row x 256 j (16 groups of 16).
// Early exit when the whole quarter is strictly below the diagonal:
// those cells are filled by k_sym from the (computed) mirror cells.
__global__ __launch_bounds__(256, 2) void k_adj(const unsigned short* __restrict__ xsw,
                                                const unsigned short* __restrict__ w1p,
                                                const float* __restrict__ b1,
                                                const float* __restrict__ W2,
                                                const float* __restrict__ b2,
                                                float* __restrict__ adj) {
  const int tid  = threadIdx.x;
  const int lane = tid & 63;
  const int w    = tid >> 6;   // 0..3
  const int l15  = lane & 15;
  const int g    = lane >> 4;  // 0..3
  const int i  = blockIdx.x * 4 + w;
  const int jq = blockIdx.y;   // 0..3

  if (jq * 256 + 255 < i) return;  // quarter entirely below diagonal

  // W1 -> regs: A[m=hid][k], hid = ht*16+l15, k = ks*32+g*8+e
  half8 w1f[4][8];
#pragma unroll
  for (int ks = 0; ks < 4; ++ks)
#pragma unroll
    for (int ht = 0; ht < 8; ++ht)
      w1f[ks][ht] = *(const half8*)(w1p + ((ks * 4 + g) * 128 + ht * 16 + l15) * 8);

  // relu(a+b1)*w2 = max(a,-b1)*w2 + b1*w2
  unsigned int nb1pk[8][2], w2pk[8][2];
  float c0 = 0.f;
#pragma unroll
  for (int ht = 0; ht < 8; ++ht) {
    const f32x4 bv = *(const f32x4*)&b1[ht * 16 + g * 4];
    const f32x4 wv = *(const f32x4*)&W2[ht * 16 + g * 4];
    c0 += bv[0] * wv[0] + bv[1] * wv[1] + bv[2] * wv[2] + bv[3] * wv[3];
    nb1pk[ht][0] = pkrtz(-bv[0], -bv[1]);
    nb1pk[ht][1] = pkrtz(-bv[2], -bv[3]);
    w2pk[ht][0] = pkrtz(wv[0], wv[1]);
    w2pk[ht][1] = pkrtz(wv[2], wv[3]);
  }
  c0 += __shfl_xor(c0, 16);
  c0 += __shfl_xor(c0, 32);
  const float B2 = b2[0] + c0;

  // xi fragments (broadcast row i)
  const unsigned char* xsb = (const unsigned char*)xsw;
  const unsigned char* xrow = xsb + i * 256;
  const int sxI = (i & 7) << 4;
  u32x4 xiu[4];
#pragma unroll
  for (int ks = 0; ks < 4; ++ks)
    xiu[ks] = *(const u32x4*)(xrow + ((ks * 64 + g * 16) ^ sxI));

  const int sxJ = (l15 & 7) << 4;
  const unsigned char* jrow = xsb + (jq * 256 + l15) * 256;
  const int kb0 = (0 * 64 + g * 16) ^ sxJ;
  const int kb1 = (1 * 64 + g * 16) ^ sxJ;
  const int kb2 = (2 * 64 + g * 16) ^ sxJ;
  const int kb3 = (3 * 64 + g * 16) ^ sxJ;

  u32x4 jr0 = *(const u32x4*)(jrow + kb0);
  u32x4 jr1 = *(const u32x4*)(jrow + kb1);
  u32x4 jr2 = *(const u32x4*)(jrow + kb2);
  u32x4 jr3 = *(const u32x4*)(jrow + kb3);

#pragma unroll 1
  for (int grp = 0; grp < 16; ++grp) {
    const unsigned char* nrow = jrow + (grp + 1) * 4096;
    f32x4 acc[8];
#pragma unroll
    for (int ht = 0; ht < 8; ++ht) acc[ht] = f32x4{0.f, 0.f, 0.f, 0.f};

    __builtin_amdgcn_s_setprio(1);
    {
      u32x4 afu;
#pragma unroll
      for (int p4 = 0; p4 < 4; ++p4) afu[p4] = absdiff_pk(jr0[p4], xiu[0][p4]);
      if (grp < 15) jr0 = *(const u32x4*)(nrow + kb0);
      const half8 af = __builtin_bit_cast(half8, afu);
#pragma unroll
      for (int ht = 0; ht < 8; ++ht)
        acc[ht] = __builtin_amdgcn_mfma_f32_16x16x32_f16(w1f[0][ht], af, acc[ht], 0, 0, 0);
    }
    {
      u32x4 afu;
#pragma unroll
      for (int p4 = 0; p4 < 4; ++p4) afu[p4] = absdiff_pk(jr1[p4], xiu[1][p4]);
      if (grp < 15) jr1 = *(const u32x4*)(nrow + kb1);
      const half8 af = __builtin_bit_cast(half8, afu);
#pragma unroll
      for (int ht = 0; ht < 8; ++ht)
        acc[ht] = __builtin_amdgcn_mfma_f32_16x16x32_f16(w1f[1][ht], af, acc[ht], 0, 0, 0);
    }
    {
      u32x4 afu;
#pragma unroll
      for (int p4 = 0; p4 < 4; ++p4) afu[p4] = absdiff_pk(jr2[p4], xiu[2][p4]);
      if (grp < 15) jr2 = *(const u32x4*)(nrow + kb2);
      const half8 af = __builtin_bit_cast(half8, afu);
#pragma unroll
      for (int ht = 0; ht < 8; ++ht)
        acc[ht] = __builtin_amdgcn_mfma_f32_16x16x32_f16(w1f[2][ht], af, acc[ht], 0, 0, 0);
    }
    {
      u32x4 afu;
#pragma unroll
      for (int p4 = 0; p4 < 4; ++p4) afu[p4] = absdiff_pk(jr3[p4], xiu[3][p4]);
      if (grp < 15) jr3 = *(const u32x4*)(nrow + kb3);
      const half8 af = __builtin_bit_cast(half8, afu);
#pragma unroll
      for (int ht = 0; ht < 8; ++ht)
        acc[ht] = __builtin_amdgcn_mfma_f32_16x16x32_f16(w1f[3][ht], af, acc[ht], 0, 0, 0);
    }
    __builtin_amdgcn_s_setprio(0);

    // dot: pkrtz+max -> 4 parallel fdot2 chains -> cross-lane reduce
    float sA = 0.f, sB = 0.f, sC = 0.f, sD = 0.f;
#pragma unroll
    for (int ht = 0; ht < 8; ht += 2) {
      unsigned int h0a = pk_max(pkrtz(acc[ht][0], acc[ht][1]), nb1pk[ht][0]);
      unsigned int h0b = pk_max(pkrtz(acc[ht][2], acc[ht][3]), nb1pk[ht][1]);
      unsigned int h1a = pk_max(pkrtz(acc[ht + 1][0], acc[ht + 1][1]), nb1pk[ht + 1][0]);
      unsigned int h1b = pk_max(pkrtz(acc[ht + 1][2], acc[ht + 1][3]), nb1pk[ht + 1][1]);
      sA = fdot2(h0a, w2pk[ht][0], sA);
      sB = fdot2(h0b, w2pk[ht][1], sB);
      sC = fdot2(h1a, w2pk[ht + 1][0], sC);
      sD = fdot2(h1b, w2pk[ht + 1][1], sD);
    }
    float s = (sA + sB) + (sC + sD);
    s += __shfl_xor(s, 16);
    s += __shfl_xor(s, 32);
    if (lane < 16) {
      const float sig = 1.f / (1.f + __expf(-(s + B2)));
      adj[i * NPT + jq * 256 + grp * 16 + l15] = sig;
    }
  }
}

// ---------------- kernel 2b: mirror lower triangle ----------------
// 2016 strictly-below-diagonal 16x16 tiles (R>C): adj[R16+r][C16+c] = adj[C16+c][R16+r].
// Per-wave LDS transpose. Every source cell is guaranteed computed by k_adj.
__global__ __launch_bounds__(256) void k_sym(float* __restrict__ adj) {
  __shared__ float lds[4][16][17];
  const int tid  = threadIdx.x;
  const int lane = tid & 63;
  const int w    = tid >> 6;
  const int t = blockIdx.x * 4 + w;  // 0..2015

  // triangular decode: t = R*(R-1)/2 + C, 1 <= R <= 63, C < R
  int R = (int)((1.0f + sqrtf(1.0f + 8.0f * (float)t)) * 0.5f);
  if (R * (R - 1) / 2 > t) --R;
  if ((R + 1) * R / 2 <= t) ++R;
  const int C = t - R * (R - 1) / 2;

  const int r16 = lane & 15;
  const int c4  = (lane >> 4) * 4;
  // read src tile: src[r16][c4..c4+3] = adj[(C*16+r16)][R*16+c4..]
  const f32x4 v = *(const f32x4*)&adj[(C * 16 + r16) * NPT + R * 16 + c4];
#pragma unroll
  for (int e = 0; e < 4; ++e) lds[w][c4 + e][r16] = v[e];
  // dest[dr][dc] = src[dc][dr] = lds[dr][dc]
  f32x4 o;
#pragma unroll
  for (int e = 0; e < 4; ++e) o[e] = lds[w][r16][c4 + e];
  *(f32x4*)&adj[(R * 16 + r16) * NPT + C * 16 + c4] = o;
}

// ---------------- kernel 2c: deg = rowsum(adj) ----------------
__global__ __launch_bounds__(256) void k_deg(const float* __restrict__ adj,
                                             float* __restrict__ deg) {
  const int lane = threadIdx.x & 63;
  const int w    = threadIdx.x >> 6;
  const int i = blockIdx.x * 4 + w;
  const float* row = &adj[i * NPT];
  float s = 0.f;
#pragma unroll
  for (int k = 0; k < 4; ++k) {
    const f32x4 v = *(const f32x4*)&row[(k * 64 + lane) * 4];
    s += (v[0] + v[1]) + (v[2] + v[3]);
  }
#pragma unroll
  for (int m = 1; m < 64; m <<= 1) s += __shfl_xor(s, m);
  if (lane == 0) deg[i] = s;
}

// ---------------- kernel 3: fused d1 (dinv-LDS prologue, MFMA, leaky epilogue) ----
// out[i][t] = leaky( dinv_i * sum_j xwghT[t][j]*(adj[i][j]*dinv_j) + bg[t] )
// grid 64 x 256 thr (4 waves). Block: 16 i x ALL 128 t. adj read exactly once.
__global__ __launch_bounds__(256) void k_d1(const float* __restrict__ adj,
                                            const unsigned short* __restrict__ xwghT,
                                            const float* __restrict__ deg,
                                            const float* __restrict__ bg,
                                            float* __restrict__ outp) {
  __shared__ unsigned short dvh[NPT];
  const int tid  = threadIdx.x;
  const int lane = tid & 63;
  const int w    = tid >> 6;
  const int l15  = lane & 15;
  const int g    = lane >> 4;
  const int i0 = blockIdx.x * 16;

#pragma unroll
  for (int it = 0; it < 4; ++it) {
    const int idx = it * 256 + tid;
    const _Float16 dh = (_Float16)rsqrtf(deg[idx]);
    dvh[idx] = __builtin_bit_cast(unsigned short, dh);
  }
  __syncthreads();

  f32x4 acc[2] = {f32x4{0.f, 0.f, 0.f, 0.f}, f32x4{0.f, 0.f, 0.f, 0.f}};
#pragma unroll 2
  for (int ch = 0; ch < 32; ++ch) {
    const int kofs = ch * 32 + g * 8;
    const f32x4 av0 = *(const f32x4*)&adj[(i0 + l15) * NPT + kofs];
    const f32x4 av1 = *(const f32x4*)&adj[(i0 + l15) * NPT + kofs + 4];
    const half2v* dq = (const half2v*)(dvh + kofs);
    u32x4 bu;
    bu[0] = __builtin_bit_cast(unsigned int,
        half2v(__builtin_bit_cast(half2v, pkrtz(av0[0], av0[1])) * dq[0]));
    bu[1] = __builtin_bit_cast(unsigned int,
        half2v(__builtin_bit_cast(half2v, pkrtz(av0[2], av0[3])) * dq[1]));
    bu[2] = __builtin_bit_cast(unsigned int,
        half2v(__builtin_bit_cast(half2v, pkrtz(av1[0], av1[1])) * dq[2]));
    bu[3] = __builtin_bit_cast(unsigned int,
        half2v(__builtin_bit_cast(half2v, pkrtz(av1[2], av1[3])) * dq[3]));
    const half8 bf = __builtin_bit_cast(half8, bu);
#pragma unroll
    for (int tt = 0; tt < 2; ++tt) {
      const int trow = w * 32 + tt * 16 + l15;
      const half8 af = *(const half8*)(xwghT + trow * NPT + kofs);
      acc[tt] = __builtin_amdgcn_mfma_f32_16x16x32_f16(af, bf, acc[tt], 0, 0, 0);
    }
  }
  const float di = rsqrtf(deg[i0 + l15]);
#pragma unroll
  for (int tt = 0; tt < 2; ++tt) {
    const int t0 = w * 32 + tt * 16;
    const f32x4 bgv = *(const f32x4*)&bg[t0 + g * 4];
    f32x4 o;
#pragma unroll
    for (int r = 0; r < 4; ++r) {
      const float v = acc[tt][r] * di + bgv[r];
      o[r] = v > 0.f ? v : 0.2f * v;
    }
    *(f32x4*)&outp[(i0 + l15) * D + t0 + g * 4] = o;
  }
}

extern "C" void kernel_launch(void* const* d_in, const int* in_sizes, int n_in,
                              void* d_out, int out_size, void* d_ws, size_t ws_size,
                              hipStream_t stream) {
  const float* x  = (const float*)d_in[0];
  const float* W1 = (const float*)d_in[1];
  const float* b1 = (const float*)d_in[2];
  const float* W2 = (const float*)d_in[3];
  const float* b2 = (const float*)d_in[4];
  const float* Wg = (const float*)d_in[5];
  const float* bg = (const float*)d_in[6];

  float* outp = (float*)d_out;                  // [1024*128]
  float* adj  = outp + NPT * D;                 // [1024*1024]
  unsigned char* ws = (unsigned char*)d_ws;
  float* deg            = (float*)ws;                               // 4KB @0
  unsigned short* xsw   = (unsigned short*)(ws + 4096);             // 256KB
  unsigned short* w1p   = (unsigned short*)(ws + 4096 + 262144);    // 32KB
  unsigned short* xwghT = (unsigned short*)(ws + 4096 + 262144 + 32768);  // 256KB

  k_prep<<<NPT, 128, 0, stream>>>(x, W1, Wg, xsw, w1p, xwghT);
  k_adj<<<dim3(256, 4), 256, 0, stream>>>(xsw, w1p, b1, W2, b2, adj);
  k_sym<<<504, 256, 0, stream>>>(adj);
  k_deg<<<256, 256, 0, stream>>>(adj, deg);
  k_d1<<<64, 256, 0, stream>>>(adj, xwghT, deg, bg, outp);
}

// Round 14
// 66.726 us; speedup vs baseline: 1.0347x; 1.0083x over previous
//
#include <hip/hip_runtime.h>
#include <hip/hip_bf16.h>
#include <math.h>

typedef __attribute__((ext_vector_type(8))) _Float16 half8;
typedef __attribute__((ext_vector_type(2))) _Float16 half2v;
typedef __attribute__((ext_vector_type(4))) float f32x4;
typedef __attribute__((ext_vector_type(4))) unsigned int u32x4;

#define NPT 1024
#define D   128

__device__ __forceinline__ unsigned int absdiff_pk(unsigned int a, unsigned int b) {
  half2v d = __builtin_bit_cast(half2v, a) - __builtin_bit_cast(half2v, b);
  return __builtin_bit_cast(unsigned int, d) & 0x7FFF7FFFu;
}
__device__ __forceinline__ unsigned int pk_max(unsigned int a, unsigned int b) {
  unsigned int r;
  asm("v_pk_max_f16 %0, %1, %2" : "=v"(r) : "v"(a), "v"(b));
  return r;
}
__device__ __forceinline__ unsigned int pkrtz(float lo, float hi) {
  return __builtin_bit_cast(unsigned int, __builtin_amdgcn_cvt_pkrtz(lo, hi));
}
__device__ __forceinline__ float fdot2(unsigned int a, unsigned int b, float c) {
  return __builtin_amdgcn_fdot2(__builtin_bit_cast(half2v, a),
                                __builtin_bit_cast(half2v, b), c, false);
}

// ---------------- kernel 1: prep ----------------
// xsw: swizzled f16 x: row i base i*256B, elem k at ((2k)^((i&7)<<4))
// w1p: fragment-ordered f16 W1: w1p[((k>>3)*128+hid)*8 + (k&7)] = W1[k][hid]
// xwghT: f16 [128 t][1024 i] transpose of x@Wg
__global__ __launch_bounds__(128) void k_prep(const float* __restrict__ x,
                                              const float* __restrict__ W1,
                                              const float* __restrict__ Wg,
                                              float* __restrict__ deg,
                                              unsigned short* __restrict__ xsw,
                                              unsigned short* __restrict__ w1p,
                                              unsigned short* __restrict__ xwghT) {
  __shared__ float xi[D];
  const int i = blockIdx.x;
  const int t = threadIdx.x;
  const float xv = x[i * D + t];
  xi[t] = xv;
  if (t == 0) deg[i] = 0.f;
  const _Float16 hv = (_Float16)xv;
  const int byte = i * 256 + ((2 * t) ^ ((i & 7) << 4));
  *(unsigned short*)((unsigned char*)xsw + byte) =
      __builtin_bit_cast(unsigned short, hv);
  if (i < 128) {  // t = k, i = hid
    const _Float16 wv = (_Float16)W1[t * 128 + i];
    w1p[((t >> 3) * 128 + i) * 8 + (t & 7)] = __builtin_bit_cast(unsigned short, wv);
  }
  __syncthreads();
  float acc = 0.f;
#pragma unroll 8
  for (int k = 0; k < D; ++k) acc += xi[k] * Wg[k * D + t];
  const _Float16 av = (_Float16)acc;
  xwghT[t * NPT + i] = __builtin_bit_cast(unsigned short, av);
}

// ---------------- kernel 2: adjacency (R7-exact: proven 45.7us, no spill) ----
// grid (256,2) x 256 thr. Wave = 1 i-row x 512 j (32 sequential groups of 16).
// Full 128-hid W1 in 128 regs (AGPR side). No LDS, no barriers.
__global__ __launch_bounds__(256, 2) void k_adj(const unsigned short* __restrict__ xsw,
                                                const unsigned short* __restrict__ w1p,
                                                const float* __restrict__ b1,
                                                const float* __restrict__ W2,
                                                const float* __restrict__ b2,
                                                float* __restrict__ adj,
                                                float* __restrict__ deg) {
  const int tid  = threadIdx.x;
  const int lane = tid & 63;
  const int w    = tid >> 6;   // 0..3
  const int l15  = lane & 15;
  const int g    = lane >> 4;  // 0..3
  const int i  = blockIdx.x * 4 + w;
  const int jq = blockIdx.y;   // 0..1, 512 j each

  // W1 -> regs: A[m=hid][k], hid = ht*16+l15, k = ks*32+g*8+e
  half8 w1f[4][8];
#pragma unroll
  for (int ks = 0; ks < 4; ++ks)
#pragma unroll
    for (int ht = 0; ht < 8; ++ht)
      w1f[ks][ht] = *(const half8*)(w1p + ((ks * 4 + g) * 128 + ht * 16 + l15) * 8);

  // relu(a+b1)*w2 = max(a,-b1)*w2 + b1*w2 : pack -b1, w2 as f16x2; c0 = sum b1*w2
  unsigned int nb1pk[8][2], w2pk[8][2];
  float c0 = 0.f;
#pragma unroll
  for (int ht = 0; ht < 8; ++ht) {
    const f32x4 bv = *(const f32x4*)&b1[ht * 16 + g * 4];
    const f32x4 wv = *(const f32x4*)&W2[ht * 16 + g * 4];
    c0 += bv[0] * wv[0] + bv[1] * wv[1] + bv[2] * wv[2] + bv[3] * wv[3];
    nb1pk[ht][0] = pkrtz(-bv[0], -bv[1]);
    nb1pk[ht][1] = pkrtz(-bv[2], -bv[3]);
    w2pk[ht][0] = pkrtz(wv[0], wv[1]);
    w2pk[ht][1] = pkrtz(wv[2], wv[3]);
  }
  c0 += __shfl_xor(c0, 16);
  c0 += __shfl_xor(c0, 32);
  const float B2 = b2[0] + c0;

  // xi fragments (broadcast row i)
  const unsigned char* xsb = (const unsigned char*)xsw;
  const unsigned char* xrow = xsb + i * 256;
  const int sxI = (i & 7) << 4;
  u32x4 xiu[4];
#pragma unroll
  for (int ks = 0; ks < 4; ++ks)
    xiu[ks] = *(const u32x4*)(xrow + ((ks * 64 + g * 16) ^ sxI));

  // per-lane j-row base: row = jq*512 + grp*16 + l15; (row&7)==(l15&7)
  const int sxJ = (l15 & 7) << 4;
  const unsigned char* jrow = xsb + (jq * 512 + l15) * 256;
  const int kb0 = (0 * 64 + g * 16) ^ sxJ;
  const int kb1 = (1 * 64 + g * 16) ^ sxJ;
  const int kb2 = (2 * 64 + g * 16) ^ sxJ;
  const int kb3 = (3 * 64 + g * 16) ^ sxJ;

  u32x4 jr0 = *(const u32x4*)(jrow + kb0);
  u32x4 jr1 = *(const u32x4*)(jrow + kb1);
  u32x4 jr2 = *(const u32x4*)(jrow + kb2);
  u32x4 jr3 = *(const u32x4*)(jrow + kb3);

  float degacc = 0.f;
#pragma unroll 1
  for (int grp = 0; grp < 32; ++grp) {
    const unsigned char* nrow = jrow + (grp + 1) * 4096;
    f32x4 acc[8];
#pragma unroll
    for (int ht = 0; ht < 8; ++ht) acc[ht] = f32x4{0.f, 0.f, 0.f, 0.f};

    __builtin_amdgcn_s_setprio(1);
    {
      u32x4 afu;
#pragma unroll
      for (int p4 = 0; p4 < 4; ++p4) afu[p4] = absdiff_pk(jr0[p4], xiu[0][p4]);
      if (grp < 31) jr0 = *(const u32x4*)(nrow + kb0);
      const half8 af = __builtin_bit_cast(half8, afu);
#pragma unroll
      for (int ht = 0; ht < 8; ++ht)
        acc[ht] = __builtin_amdgcn_mfma_f32_16x16x32_f16(w1f[0][ht], af, acc[ht], 0, 0, 0);
    }
    {
      u32x4 afu;
#pragma unroll
      for (int p4 = 0; p4 < 4; ++p4) afu[p4] = absdiff_pk(jr1[p4], xiu[1][p4]);
      if (grp < 31) jr1 = *(const u32x4*)(nrow + kb1);
      const half8 af = __builtin_bit_cast(half8, afu);
#pragma unroll
      for (int ht = 0; ht < 8; ++ht)
        acc[ht] = __builtin_amdgcn_mfma_f32_16x16x32_f16(w1f[1][ht], af, acc[ht], 0, 0, 0);
    }
    {
      u32x4 afu;
#pragma unroll
      for (int p4 = 0; p4 < 4; ++p4) afu[p4] = absdiff_pk(jr2[p4], xiu[2][p4]);
      if (grp < 31) jr2 = *(const u32x4*)(nrow + kb2);
      const half8 af = __builtin_bit_cast(half8, afu);
#pragma unroll
      for (int ht = 0; ht < 8; ++ht)
        acc[ht] = __builtin_amdgcn_mfma_f32_16x16x32_f16(w1f[2][ht], af, acc[ht], 0, 0, 0);
    }
    {
      u32x4 afu;
#pragma unroll
      for (int p4 = 0; p4 < 4; ++p4) afu[p4] = absdiff_pk(jr3[p4], xiu[3][p4]);
      if (grp < 31) jr3 = *(const u32x4*)(nrow + kb3);
      const half8 af = __builtin_bit_cast(half8, afu);
#pragma unroll
      for (int ht = 0; ht < 8; ++ht)
        acc[ht] = __builtin_amdgcn_mfma_f32_16x16x32_f16(w1f[3][ht], af, acc[ht], 0, 0, 0);
    }
    __builtin_amdgcn_s_setprio(0);

    // dot: pkrtz+max -> 4 parallel fdot2 chains -> cross-lane reduce
    float sA = 0.f, sB = 0.f, sC = 0.f, sD = 0.f;
#pragma unroll
    for (int ht = 0; ht < 8; ht += 2) {
      unsigned int h0a = pk_max(pkrtz(acc[ht][0], acc[ht][1]), nb1pk[ht][0]);
      unsigned int h0b = pk_max(pkrtz(acc[ht][2], acc[ht][3]), nb1pk[ht][1]);
      unsigned int h1a = pk_max(pkrtz(acc[ht + 1][0], acc[ht + 1][1]), nb1pk[ht + 1][0]);
      unsigned int h1b = pk_max(pkrtz(acc[ht + 1][2], acc[ht + 1][3]), nb1pk[ht + 1][1]);
      sA = fdot2(h0a, w2pk[ht][0], sA);
      sB = fdot2(h0b, w2pk[ht][1], sB);
      sC = fdot2(h1a, w2pk[ht + 1][0], sC);
      sD = fdot2(h1b, w2pk[ht + 1][1], sD);
    }
    float s = (sA + sB) + (sC + sD);
    s += __shfl_xor(s, 16);
    s += __shfl_xor(s, 32);
    if (lane < 16) {
      const float sig = 1.f / (1.f + __expf(-(s + B2)));
      adj[i * NPT + jq * 512 + grp * 16 + l15] = sig;
      degacc += sig;
    }
  }
  if (lane < 16) {
#pragma unroll
    for (int m = 1; m <= 8; m <<= 1) degacc += __shfl_xor(degacc, m);
    if (l15 == 0) atomicAdd(&deg[i], degacc);
  }
}

// ---------------- kernel 3: fused d1 (dinv-LDS prologue, MFMA, leaky epilogue) ----
// out[i][t] = leaky( dinv_i * sum_j xwghT[t][j]*(adj[i][j]*dinv_j) + bg[t] )
// grid 64 x 256 thr (4 waves). Block: 16 i x ALL 128 t. adj read exactly once.
__global__ __launch_bounds__(256) void k_d1(const float* __restrict__ adj,
                                            const unsigned short* __restrict__ xwghT,
                                            const float* __restrict__ deg,
                                            const float* __restrict__ bg,
                                            float* __restrict__ outp) {
  __shared__ unsigned short dvh[NPT];
  const int tid  = threadIdx.x;
  const int lane = tid & 63;
  const int w    = tid >> 6;
  const int l15  = lane & 15;
  const int g    = lane >> 4;
  const int i0 = blockIdx.x * 16;

#pragma unroll
  for (int it = 0; it < 4; ++it) {
    const int idx = it * 256 + tid;
    const _Float16 dh = (_Float16)rsqrtf(deg[idx]);
    dvh[idx] = __builtin_bit_cast(unsigned short, dh);
  }
  __syncthreads();

  f32x4 acc[2] = {f32x4{0.f, 0.f, 0.f, 0.f}, f32x4{0.f, 0.f, 0.f, 0.f}};
#pragma unroll 2
  for (int ch = 0; ch < 32; ++ch) {
    const int kofs = ch * 32 + g * 8;
    const f32x4 av0 = *(const f32x4*)&adj[(i0 + l15) * NPT + kofs];
    const f32x4 av1 = *(const f32x4*)&adj[(i0 + l15) * NPT + kofs + 4];
    const half2v* dq = (const half2v*)(dvh + kofs);
    u32x4 bu;
    bu[0] = __builtin_bit_cast(unsigned int,
        half2v(__builtin_bit_cast(half2v, pkrtz(av0[0], av0[1])) * dq[0]));
    bu[1] = __builtin_bit_cast(unsigned int,
        half2v(__builtin_bit_cast(half2v, pkrtz(av0[2], av0[3])) * dq[1]));
    bu[2] = __builtin_bit_cast(unsigned int,
        half2v(__builtin_bit_cast(half2v, pkrtz(av1[0], av1[1])) * dq[2]));
    bu[3] = __builtin_bit_cast(unsigned int,
        half2v(__builtin_bit_cast(half2v, pkrtz(av1[2], av1[3])) * dq[3]));
    const half8 bf = __builtin_bit_cast(half8, bu);
#pragma unroll
    for (int tt = 0; tt < 2; ++tt) {
      const int trow = w * 32 + tt * 16 + l15;
      const half8 af = *(const half8*)(xwghT + trow * NPT + kofs);
      acc[tt] = __builtin_amdgcn_mfma_f32_16x16x32_f16(af, bf, acc[tt], 0, 0, 0);
    }
  }
  const float di = rsqrtf(deg[i0 + l15]);
#pragma unroll
  for (int tt = 0; tt < 2; ++tt) {
    const int t0 = w * 32 + tt * 16;
    const f32x4 bgv = *(const f32x4*)&bg[t0 + g * 4];
    f32x4 o;
#pragma unroll
    for (int r = 0; r < 4; ++r) {
      const float v = acc[tt][r] * di + bgv[r];
      o[r] = v > 0.f ? v : 0.2f * v;
    }
    *(f32x4*)&outp[(i0 + l15) * D + t0 + g * 4] = o;
  }
}

extern "C" void kernel_launch(void* const* d_in, const int* in_sizes, int n_in,
                              void* d_out, int out_size, void* d_ws, size_t ws_size,
                              hipStream_t stream) {
  const float* x  = (const float*)d_in[0];
  const float* W1 = (const float*)d_in[1];
  const float* b1 = (const float*)d_in[2];
  const float* W2 = (const float*)d_in[3];
  const float* b2 = (const float*)d_in[4];
  const float* Wg = (const float*)d_in[5];
  const float* bg = (const float*)d_in[6];

  float* outp = (float*)d_out;                  // [1024*128]
  float* adj  = outp + NPT * D;                 // [1024*1024]
  unsigned char* ws = (unsigned char*)d_ws;
  float* deg            = (float*)ws;                               // 4KB @0
  unsigned short* xsw   = (unsigned short*)(ws + 4096);             // 256KB
  unsigned short* w1p   = (unsigned short*)(ws + 4096 + 262144);    // 32KB
  unsigned short* xwghT = (unsigned short*)(ws + 4096 + 262144 + 32768);  // 256KB

  k_prep<<<NPT, 128, 0, stream>>>(x, W1, Wg, deg, xsw, w1p, xwghT);
  k_adj<<<dim3(256, 2), 256, 0, stream>>>(xsw, w1p, b1, W2, b2, adj, deg);
  k_d1<<<64, 256, 0, stream>>>(adj, xwghT, deg, bg, outp);
}

// Round 15
// 61.328 us; speedup vs baseline: 1.1257x; 1.0880x over previous
//
#include <hip/hip_runtime.h>
#include <hip/hip_bf16.h>
#include <math.h>

typedef __attribute__((ext_vector_type(8))) _Float16 half8;
typedef __attribute__((ext_vector_type(2))) _Float16 half2v;
typedef __attribute__((ext_vector_type(4))) float f32x4;
typedef __attribute__((ext_vector_type(4))) unsigned int u32x4;

#define NPT 1024
#define D   128

__device__ __forceinline__ unsigned int absdiff_pk(unsigned int a, unsigned int b) {
  half2v d = __builtin_bit_cast(half2v, a) - __builtin_bit_cast(half2v, b);
  return __builtin_bit_cast(unsigned int, d) & 0x7FFF7FFFu;
}
__device__ __forceinline__ unsigned int pk_max(unsigned int a, unsigned int b) {
  unsigned int r;
  asm("v_pk_max_f16 %0, %1, %2" : "=v"(r) : "v"(a), "v"(b));
  return r;
}
__device__ __forceinline__ unsigned int pkrtz(float lo, float hi) {
  return __builtin_bit_cast(unsigned int, __builtin_amdgcn_cvt_pkrtz(lo, hi));
}
__device__ __forceinline__ float fdot2(unsigned int a, unsigned int b, float c) {
  return __builtin_amdgcn_fdot2(__builtin_bit_cast(half2v, a),
                                __builtin_bit_cast(half2v, b), c, false);
}

// ---------------- kernel 1: prep ----------------
// xsw: swizzled f16 x: row i base i*256B, elem k at ((2k)^((i&7)<<4))
// w1p: fragment-ordered f16 W1: w1p[((k>>3)*128+hid)*8 + (k&7)] = W1[k][hid]
// xwghT: f16 [128 t][1024 i] transpose of x@Wg
__global__ __launch_bounds__(128) void k_prep(const float* __restrict__ x,
                                              const float* __restrict__ W1,
                                              const float* __restrict__ Wg,
                                              float* __restrict__ deg,
                                              unsigned short* __restrict__ xsw,
                                              unsigned short* __restrict__ w1p,
                                              unsigned short* __restrict__ xwghT) {
  __shared__ float xi[D];
  const int i = blockIdx.x;
  const int t = threadIdx.x;
  const float xv = x[i * D + t];
  xi[t] = xv;
  if (t == 0) deg[i] = 0.f;
  const _Float16 hv = (_Float16)xv;
  const int byte = i * 256 + ((2 * t) ^ ((i & 7) << 4));
  *(unsigned short*)((unsigned char*)xsw + byte) =
      __builtin_bit_cast(unsigned short, hv);
  if (i < 128) {  // t = k, i = hid
    const _Float16 wv = (_Float16)W1[t * 128 + i];
    w1p[((t >> 3) * 128 + i) * 8 + (t & 7)] = __builtin_bit_cast(unsigned short, wv);
  }
  __syncthreads();
  float a0 = 0.f, a1 = 0.f, a2 = 0.f, a3 = 0.f;  // 4 parallel chains (ILP)
#pragma unroll 8
  for (int k = 0; k < D; k += 4) {
    a0 += xi[k + 0] * Wg[(k + 0) * D + t];
    a1 += xi[k + 1] * Wg[(k + 1) * D + t];
    a2 += xi[k + 2] * Wg[(k + 2) * D + t];
    a3 += xi[k + 3] * Wg[(k + 3) * D + t];
  }
  const _Float16 av = (_Float16)((a0 + a1) + (a2 + a3));
  xwghT[t * NPT + i] = __builtin_bit_cast(unsigned short, av);
}

// ---------------- kernel 2: adjacency (R7 core + rot stagger + LDS-deferred store) ----
// grid (256,2) x 256 thr. Wave = 1 i-row x 512 j (32 groups of 16, rotated start).
// Full 128-hid W1 in 128 regs. Per-group: MFMA+dot+reduce -> 1 LDS write.
// Epilogue: all-lane sigmoid (8/lane) + 2 coalesced 1KB adj stores + 1 deg atomic.
__global__ __launch_bounds__(256, 2) void k_adj(const unsigned short* __restrict__ xsw,
                                                const unsigned short* __restrict__ w1p,
                                                const float* __restrict__ b1,
                                                const float* __restrict__ W2,
                                                const float* __restrict__ b2,
                                                float* __restrict__ adj,
                                                float* __restrict__ deg) {
  __shared__ float sbuf[4][512];
  const int tid  = threadIdx.x;
  const int lane = tid & 63;
  const int w    = tid >> 6;   // 0..3
  const int l15  = lane & 15;
  const int g    = lane >> 4;  // 0..3
  const int i  = blockIdx.x * 4 + w;
  const int jq = blockIdx.y;   // 0..1, 512 j each
  const int rot = ((w * 2 + jq) & 7) * 4;  // anti-phase co-resident waves

  // W1 -> regs: A[m=hid][k], hid = ht*16+l15, k = ks*32+g*8+e
  half8 w1f[4][8];
#pragma unroll
  for (int ks = 0; ks < 4; ++ks)
#pragma unroll
    for (int ht = 0; ht < 8; ++ht)
      w1f[ks][ht] = *(const half8*)(w1p + ((ks * 4 + g) * 128 + ht * 16 + l15) * 8);

  // relu(a+b1)*w2 = max(a,-b1)*w2 + b1*w2 : c0 = sum b1*w2
  unsigned int nb1pk[8][2], w2pk[8][2];
  float c0 = 0.f;
#pragma unroll
  for (int ht = 0; ht < 8; ++ht) {
    const f32x4 bv = *(const f32x4*)&b1[ht * 16 + g * 4];
    const f32x4 wv = *(const f32x4*)&W2[ht * 16 + g * 4];
    c0 += bv[0] * wv[0] + bv[1] * wv[1] + bv[2] * wv[2] + bv[3] * wv[3];
    nb1pk[ht][0] = pkrtz(-bv[0], -bv[1]);
    nb1pk[ht][1] = pkrtz(-bv[2], -bv[3]);
    w2pk[ht][0] = pkrtz(wv[0], wv[1]);
    w2pk[ht][1] = pkrtz(wv[2], wv[3]);
  }
  c0 += __shfl_xor(c0, 16);
  c0 += __shfl_xor(c0, 32);
  const float B2 = b2[0] + c0;

  // xi fragments (broadcast row i)
  const unsigned char* xsb = (const unsigned char*)xsw;
  const unsigned char* xrow = xsb + i * 256;
  const int sxI = (i & 7) << 4;
  u32x4 xiu[4];
#pragma unroll
  for (int ks = 0; ks < 4; ++ks)
    xiu[ks] = *(const u32x4*)(xrow + ((ks * 64 + g * 16) ^ sxI));

  // per-lane j-row base: row = jq*512 + grp*16 + l15; (row&7)==(l15&7)
  const int sxJ = (l15 & 7) << 4;
  const unsigned char* jrow = xsb + (jq * 512 + l15) * 256;
  const int kb0 = (0 * 64 + g * 16) ^ sxJ;
  const int kb1 = (1 * 64 + g * 16) ^ sxJ;
  const int kb2 = (2 * 64 + g * 16) ^ sxJ;
  const int kb3 = (3 * 64 + g * 16) ^ sxJ;

  u32x4 jr0 = *(const u32x4*)(jrow + rot * 4096 + kb0);
  u32x4 jr1 = *(const u32x4*)(jrow + rot * 4096 + kb1);
  u32x4 jr2 = *(const u32x4*)(jrow + rot * 4096 + kb2);
  u32x4 jr3 = *(const u32x4*)(jrow + rot * 4096 + kb3);

#pragma unroll 1
  for (int q = 0; q < 32; ++q) {
    const int grp = (q + rot) & 31;
    const unsigned char* nrow = jrow + (((grp + 1) & 31) * 4096);
    f32x4 acc[8];
#pragma unroll
    for (int ht = 0; ht < 8; ++ht) acc[ht] = f32x4{0.f, 0.f, 0.f, 0.f};

    __builtin_amdgcn_s_setprio(1);
    {
      u32x4 afu;
#pragma unroll
      for (int p4 = 0; p4 < 4; ++p4) afu[p4] = absdiff_pk(jr0[p4], xiu[0][p4]);
      if (q < 31) jr0 = *(const u32x4*)(nrow + kb0);
      const half8 af = __builtin_bit_cast(half8, afu);
#pragma unroll
      for (int ht = 0; ht < 8; ++ht)
        acc[ht] = __builtin_amdgcn_mfma_f32_16x16x32_f16(w1f[0][ht], af, acc[ht], 0, 0, 0);
    }
    {
      u32x4 afu;
#pragma unroll
      for (int p4 = 0; p4 < 4; ++p4) afu[p4] = absdiff_pk(jr1[p4], xiu[1][p4]);
      if (q < 31) jr1 = *(const u32x4*)(nrow + kb1);
      const half8 af = __builtin_bit_cast(half8, afu);
#pragma unroll
      for (int ht = 0; ht < 8; ++ht)
        acc[ht] = __builtin_amdgcn_mfma_f32_16x16x32_f16(w1f[1][ht], af, acc[ht], 0, 0, 0);
    }
    {
      u32x4 afu;
#pragma unroll
      for (int p4 = 0; p4 < 4; ++p4) afu[p4] = absdiff_pk(jr2[p4], xiu[2][p4]);
      if (q < 31) jr2 = *(const u32x4*)(nrow + kb2);
      const half8 af = __builtin_bit_cast(half8, afu);
#pragma unroll
      for (int ht = 0; ht < 8; ++ht)
        acc[ht] = __builtin_amdgcn_mfma_f32_16x16x32_f16(w1f[2][ht], af, acc[ht], 0, 0, 0);
    }
    {
      u32x4 afu;
#pragma unroll
      for (int p4 = 0; p4 < 4; ++p4) afu[p4] = absdiff_pk(jr3[p4], xiu[3][p4]);
      if (q < 31) jr3 = *(const u32x4*)(nrow + kb3);
      const half8 af = __builtin_bit_cast(half8, afu);
#pragma unroll
      for (int ht = 0; ht < 8; ++ht)
        acc[ht] = __builtin_amdgcn_mfma_f32_16x16x32_f16(w1f[3][ht], af, acc[ht], 0, 0, 0);
    }
    __builtin_amdgcn_s_setprio(0);

    // dot: pkrtz+max -> 4 parallel fdot2 chains -> cross-lane reduce
    float sA = 0.f, sB = 0.f, sC = 0.f, sD = 0.f;
#pragma unroll
    for (int ht = 0; ht < 8; ht += 2) {
      unsigned int h0a = pk_max(pkrtz(acc[ht][0], acc[ht][1]), nb1pk[ht][0]);
      unsigned int h0b = pk_max(pkrtz(acc[ht][2], acc[ht][3]), nb1pk[ht][1]);
      unsigned int h1a = pk_max(pkrtz(acc[ht + 1][0], acc[ht + 1][1]), nb1pk[ht + 1][0]);
      unsigned int h1b = pk_max(pkrtz(acc[ht + 1][2], acc[ht + 1][3]), nb1pk[ht + 1][1]);
      sA = fdot2(h0a, w2pk[ht][0], sA);
      sB = fdot2(h0b, w2pk[ht][1], sB);
      sC = fdot2(h1a, w2pk[ht + 1][0], sC);
      sD = fdot2(h1b, w2pk[ht + 1][1], sD);
    }
    float s = (sA + sB) + (sC + sD);
    s += __shfl_xor(s, 16);
    s += __shfl_xor(s, 32);
    if (lane < 16) sbuf[w][grp * 16 + l15] = s;  // defer sigmoid/store
  }

  // epilogue: all-lane sigmoid + coalesced stores + one deg atomic per wave
  float degacc = 0.f;
  const float* sb = sbuf[w];
#pragma unroll
  for (int it = 0; it < 2; ++it) {
    const f32x4 sv = *(const f32x4*)&sb[it * 256 + lane * 4];
    f32x4 ov;
#pragma unroll
    for (int e = 0; e < 4; ++e) {
      ov[e] = 1.f / (1.f + __expf(-(sv[e] + B2)));
      degacc += ov[e];
    }
    *(f32x4*)&adj[i * NPT + jq * 512 + it * 256 + lane * 4] = ov;
  }
#pragma unroll
  for (int m = 1; m < 64; m <<= 1) degacc += __shfl_xor(degacc, m);
  if (lane == 0) atomicAdd(&deg[i], degacc);
}

// ---------------- kernel 3: fused d1 (dinv-LDS prologue, MFMA, leaky epilogue) ----
// out[i][t] = leaky( dinv_i * sum_j xwghT[t][j]*(adj[i][j]*dinv_j) + bg[t] )
// grid 64 x 256 thr (4 waves). Block: 16 i x ALL 128 t. adj read exactly once.
__global__ __launch_bounds__(256) void k_d1(const float* __restrict__ adj,
                                            const unsigned short* __restrict__ xwghT,
                                            const float* __restrict__ deg,
                                            const float* __restrict__ bg,
                                            float* __restrict__ outp) {
  __shared__ unsigned short dvh[NPT];
  const int tid  = threadIdx.x;
  const int lane = tid & 63;
  const int w    = tid >> 6;
  const int l15  = lane & 15;
  const int g    = lane >> 4;
  const int i0 = blockIdx.x * 16;

#pragma unroll
  for (int it = 0; it < 4; ++it) {
    const int idx = it * 256 + tid;
    const _Float16 dh = (_Float16)rsqrtf(deg[idx]);
    dvh[idx] = __builtin_bit_cast(unsigned short, dh);
  }
  __syncthreads();

  f32x4 acc[2] = {f32x4{0.f, 0.f, 0.f, 0.f}, f32x4{0.f, 0.f, 0.f, 0.f}};
#pragma unroll 2
  for (int ch = 0; ch < 32; ++ch) {
    const int kofs = ch * 32 + g * 8;
    const f32x4 av0 = *(const f32x4*)&adj[(i0 + l15) * NPT + kofs];
    const f32x4 av1 = *(const f32x4*)&adj[(i0 + l15) * NPT + kofs + 4];
    const half2v* dq = (const half2v*)(dvh + kofs);
    u32x4 bu;
    bu[0] = __builtin_bit_cast(unsigned int,
        half2v(__builtin_bit_cast(half2v, pkrtz(av0[0], av0[1])) * dq[0]));
    bu[1] = __builtin_bit_cast(unsigned int,
        half2v(__builtin_bit_cast(half2v, pkrtz(av0[2], av0[3])) * dq[1]));
    bu[2] = __builtin_bit_cast(unsigned int,
        half2v(__builtin_bit_cast(half2v, pkrtz(av1[0], av1[1])) * dq[2]));
    bu[3] = __builtin_bit_cast(unsigned int,
        half2v(__builtin_bit_cast(half2v, pkrtz(av1[2], av1[3])) * dq[3]));
    const half8 bf = __builtin_bit_cast(half8, bu);
#pragma unroll
    for (int tt = 0; tt < 2; ++tt) {
      const int trow = w * 32 + tt * 16 + l15;
      const half8 af = *(const half8*)(xwghT + trow * NPT + kofs);
      acc[tt] = __builtin_amdgcn_mfma_f32_16x16x32_f16(af, bf, acc[tt], 0, 0, 0);
    }
  }
  const float di = rsqrtf(deg[i0 + l15]);
#pragma unroll
  for (int tt = 0; tt < 2; ++tt) {
    const int t0 = w * 32 + tt * 16;
    const f32x4 bgv = *(const f32x4*)&bg[t0 + g * 4];
    f32x4 o;
#pragma unroll
    for (int r = 0; r < 4; ++r) {
      const float v = acc[tt][r] * di + bgv[r];
      o[r] = v > 0.f ? v : 0.2f * v;
    }
    *(f32x4*)&outp[(i0 + l15) * D + t0 + g * 4] = o;
  }
}

extern "C" void kernel_launch(void* const* d_in, const int* in_sizes, int n_in,
                              void* d_out, int out_size, void* d_ws, size_t ws_size,
                              hipStream_t stream) {
  const float* x  = (const float*)d_in[0];
  const float* W1 = (const float*)d_in[1];
  const float* b1 = (const float*)d_in[2];
  const float* W2 = (const float*)d_in[3];
  const float* b2 = (const float*)d_in[4];
  const float* Wg = (const float*)d_in[5];
  const float* bg = (const float*)d_in[6];

  float* outp = (float*)d_out;                  // [1024*128]
  float* adj  = outp + NPT * D;                 // [1024*1024]
  unsigned char* ws = (unsigned char*)d_ws;
  float* deg            = (float*)ws;                               // 4KB @0
  unsigned short* xsw   = (unsigned short*)(ws + 4096);             // 256KB
  unsigned short* w1p   = (unsigned short*)(ws + 4096 + 262144);    // 32KB
  unsigned short* xwghT = (unsigned short*)(ws + 4096 + 262144 + 32768);  // 256KB

  k_prep<<<NPT, 128, 0, stream>>>(x, W1, Wg, deg, xsw, w1p, xwghT);
  k_adj<<<dim3(256, 2), 256, 0, stream>>>(xsw, w1p, b1, W2, b2, adj, deg);
  k_d1<<<64, 256, 0, stream>>>(adj, xwghT, deg, bg, outp);
}